// Round 9
// baseline (138.505 us; speedup 1.0000x reference)
//
#include <hip/hip_runtime.h>
#include <math.h>

// Problem constants: B=2, N=1024, Din=64, D=64, K=24
#define BB 2
#define NN 1024
#define DD 64
#define KK 24
#define NPTS (BB * NN)  // 2048

#if __has_builtin(__builtin_amdgcn_exp2f)
#define EXP2(x) __builtin_amdgcn_exp2f(x)
#else
#define EXP2(x) exp2f(x)
#endif

typedef short short8 __attribute__((ext_vector_type(8)));     // 8 bf16 (4 VGPR)
typedef float floatx16 __attribute__((ext_vector_type(16)));  // 32x32 acc
typedef float floatx4 __attribute__((ext_vector_type(4)));    // 16x16 acc

static __device__ __forceinline__ unsigned short bf_rne(float x) {
    unsigned u = __float_as_uint(x);
    u += 0x7FFFu + ((u >> 16) & 1u);
    return (unsigned short)(u >> 16);
}
// pack trunc-bf16(hi),trunc-bf16(lo) into one dword with a single v_perm_b32
static __device__ __forceinline__ unsigned bfpack(float hi, float lo) {
    return __builtin_amdgcn_perm(__float_as_uint(hi), __float_as_uint(lo), 0x07060302u);
}

union U8 { unsigned u[4]; short8 s8; };

// ---------------------------------------------------------------------------
// Workspace: feat [2048][64] f32 @0 (512K) | idx [2048][24] i32 @524288 (192K)
//            rwB [4096][4] bf16 @720896 (32K)  rwB[J] = {rw0,rw1,rw2,rb}*log2e
// ---------------------------------------------------------------------------

__global__ __launch_bounds__(256) void prep_mlp_knn_kernel(
    const float* __restrict__ feature, const float* __restrict__ xyz,
    const float* __restrict__ pw1, const float* __restrict__ pb1,
    const float* __restrict__ pw2, const float* __restrict__ pb2,
    const float* __restrict__ rw, const float* __restrict__ rb,
    float* __restrict__ feat, int* __restrict__ idx_out,
    unsigned short* __restrict__ rwB) {
    int bid = blockIdx.x;
    int tid = threadIdx.x;

    if (bid < 512) {
        // ---- MLP: feat = relu(relu(feature@pw1+pb1)@pw2+pb2), 4 rows/block
        int r = tid >> 6;
        int d = tid & 63;
        int row = bid * 4 + r;
        __shared__ float s_in[4][64];
        __shared__ float s_h[4][64];
        s_in[r][d] = feature[row * 64 + d];
        __syncthreads();
        float h = pb1[d];
#pragma unroll
        for (int i = 0; i < 64; i++) h = __builtin_fmaf(s_in[r][i], pw1[i * 64 + d], h);
        h = fmaxf(h, 0.f);
        s_h[r][d] = h;
        __syncthreads();
        float f = pb2[d];
#pragma unroll
        for (int i = 0; i < 64; i++) f = __builtin_fmaf(s_h[r][i], pw2[i * 64 + d], f);
        f = fmaxf(f, 0.f);
        feat[row * 64 + d] = f;
    } else if (bid < 528) {
        // ---- rwB[J] = bf16{rw[0][J],rw[1][J],rw[2][J],rb[J]} * log2(e)
        const float LOG2E = 1.4426950408889634f;
        int t = (bid - 512) * 256 + tid;  // 0..4095
        unsigned b0 = bf_rne(rw[t] * LOG2E);
        unsigned b1 = bf_rne(rw[4096 + t] * LOG2E);
        unsigned b2 = bf_rne(rw[8192 + t] * LOG2E);
        unsigned b3 = bf_rne(rb[t] * LOG2E);
        uint2 v;
        v.x = b0 | (b1 << 16);
        v.y = b2 | (b3 << 16);
        *(uint2*)(rwB + 4 * t) = v;
    } else {
        // ---- KNN: one wave per point, iterative argmin (24 rounds)
        int w = tid >> 6;
        int lane = tid & 63;
        int pt = (bid - 528) * 4 + w;
        int b = pt >> 10;
        int n = pt & 1023;
        const float* xb = xyz + (size_t)b * NN * 3;
        float xn = xb[n * 3 + 0], yn = xb[n * 3 + 1], zn = xb[n * 3 + 2];
        float sqn = xn * xn + yn * yn + zn * zn;
        float dist[16];
#pragma unroll
        for (int c = 0; c < 16; c++) {
            int m = c * 64 + lane;
            float xm = xb[m * 3 + 0], ym = xb[m * 3 + 1], zm = xb[m * 3 + 2];
            float sqm = xm * xm + ym * ym + zm * zm;
            float dot = xn * xm + yn * ym + zn * zm;
            dist[c] = sqn + sqm - 2.0f * dot;
        }
        for (int r = 0; r < KK; r++) {
            float best = 3.4e38f;
            int bi = 1 << 30;
#pragma unroll
            for (int c = 0; c < 16; c++) {
                if (dist[c] < best) {
                    best = dist[c];
                    bi = c * 64 + lane;
                }
            }
#pragma unroll
            for (int off = 32; off >= 1; off >>= 1) {
                float ob = __shfl_down(best, off);
                int oi = __shfl_down(bi, off);
                if (ob < best || (ob == best && oi < bi)) {
                    best = ob;
                    bi = oi;
                }
            }
            bi = __shfl(bi, 0);
            if ((bi & 63) == lane) dist[bi >> 6] = 3.4e38f;
            if (lane == 0) idx_out[pt * KK + r] = bi;
        }
    }
}

// MFMA-based fused kernel. One block per point, 4 waves.
// GEMM1 (32x32x16 bf16): logits[k=0..23][J] = rel4[k][0..3] @ rwB[0..3][J],
//   J = j*64+d, one MFMA per 32-J tile (K=4 of 16 used).
//   C layout (m74): col=lane&31 -> J, row=(reg&3)+8*(reg>>2)+4*(lane>>5) -> k.
// exp2 on accumulators, trunc-bf16, store e_t[d][mm] (mm = j_local*24+k).
// GEMM2 (16x16x32 bf16): [gv;1](2x192-chunk) @ e_t(192x16) accumulated over
//   8 chunks -> row0 = numer, row1 = denom per d. Wave w owns d in [16w,16w+16).
//   A layout (m120): m=lane&15, k=(lane>>4)*8+reg; B: n=lane&15, k=(lane>>4)*8+reg.
__global__ __launch_bounds__(256, 4) void agg_kernel(const float* __restrict__ xyz,
                                                     const float* __restrict__ feat,
                                                     const int* __restrict__ idx,
                                                     const unsigned short* __restrict__ rwB,
                                                     const float* __restrict__ sw,
                                                     const float* __restrict__ sb,
                                                     float* __restrict__ out) {
    int pt = blockIdx.x;
    int b = pt >> 10;
    int n = pt & 1023;
    int tid = threadIdx.x;
    int w = tid >> 6;
    int lane = tid & 63;
    int n16 = lane & 15, q4 = lane >> 4;
    int n32 = lane & 31, h = lane >> 5;

    __shared__ unsigned short s_et[64][196];   // e chunk, [d][mm], 25088 B
    __shared__ unsigned short s_gv[KK * 64];   // gv bf16, mm = j*24+k, 3072 B
    __shared__ unsigned short s_rel4[32][4];   // {relx,rely,relz,1} bf16, rows>=24 zero
    __shared__ float s_pre[64];
    __shared__ float s_red[4][64];

    const float* xb = xyz + (size_t)b * NN * 3;

    // ---- staging
    if (tid < 32) {
        if (tid < KK) {
            int nb = idx[pt * KK + tid];
            s_rel4[tid][0] = bf_rne(xb[nb * 3 + 0] - xb[n * 3 + 0]);
            s_rel4[tid][1] = bf_rne(xb[nb * 3 + 1] - xb[n * 3 + 1]);
            s_rel4[tid][2] = bf_rne(xb[nb * 3 + 2] - xb[n * 3 + 2]);
            s_rel4[tid][3] = 0x3F80;  // 1.0 bf16 (bias row)
        } else {
            s_rel4[tid][0] = 0; s_rel4[tid][1] = 0; s_rel4[tid][2] = 0; s_rel4[tid][3] = 0;
        }
    }
#pragma unroll
    for (int i = 0; i < 6; i++) {
        int flat = tid + 256 * i;       // mm = j*24 + k
        int j = flat / 24;
        int k = flat - 24 * j;
        int nb = idx[pt * KK + k];
        s_gv[flat] = bf_rne(feat[((size_t)b * NN + nb) * 64 + j]);
    }
    __syncthreads();

    // GEMM1 A-fragment (constant for whole point): A[m=n32][kk=h*8+reg]
    short8 afrag;
    {
        unsigned a01 = 0, a23 = 0;
        if (h == 0) {
            const unsigned* p = (const unsigned*)&s_rel4[n32][0];
            a01 = p[0];
            a23 = p[1];
        }
        U8 u; u.u[0] = a01; u.u[1] = a23; u.u[2] = 0; u.u[3] = 0;
        afrag = u.s8;
    }

    floatx4 c2 = (floatx4)(0.0f);  // GEMM2 acc: row0=numer,row1=denom for d=16w+n16
    const floatx16 z16 = (floatx16)(0.0f);
    const unsigned ONES = 0x3F803F80u;

    for (int c = 0; c < 8; c++) {
        // ======== phase A: GEMM1 + exp for this chunk (j in [8c,8c+8)) ========
        int nt0 = 16 * c + 4 * w;
        uint2 gb = *(const uint2*)(rwB + 4 * ((nt0 << 5) + n32));  // tile 0 prefetch
#pragma unroll 1
        for (int t = 0; t < 4; t++) {
            int nt = nt0 + t;
            uint2 gbn = gb;
            if (t < 3) gbn = *(const uint2*)(rwB + 4 * (((nt + 1) << 5) + n32));
            short8 bfrag;
            {
                unsigned b01 = (h == 0) ? gb.x : 0u;
                unsigned b23 = (h == 0) ? gb.y : 0u;
                U8 u; u.u[0] = b01; u.u[1] = b23; u.u[2] = 0; u.u[3] = 0;
                bfrag = u.s8;
            }
            floatx16 acc = __builtin_amdgcn_mfma_f32_32x32x16_bf16(afrag, bfrag, z16, 0, 0, 0);
            int jl = (nt >> 1) - 8 * c;          // uniform per tile
            int d = ((nt & 1) << 5) + n32;
#pragma unroll
            for (int g = 0; g < 3; g++) {        // k = 8g+4h+{0..3} (all < 24)
                float e0 = EXP2(acc[4 * g + 0]);
                float e1 = EXP2(acc[4 * g + 1]);
                float e2 = EXP2(acc[4 * g + 2]);
                float e3 = EXP2(acc[4 * g + 3]);
                uint2 pv;
                pv.x = bfpack(e1, e0);
                pv.y = bfpack(e3, e2);
                int mm = jl * 24 + 8 * g + 4 * h;
                *(uint2*)&s_et[d][mm] = pv;
            }
            gb = gbn;
        }
        __syncthreads();
        // ======== phase B: GEMM2 over this chunk's 192 m-rows ========
#pragma unroll
        for (int ks = 0; ks < 6; ks++) {
            int mmb = 32 * ks + 8 * q4;
            // A-frag: gv row (m==0), ones (m==1), zero otherwise
            uint4 gvv = *(const uint4*)&s_gv[192 * c + mmb];
            short8 ag;
            {
                U8 u;
                u.u[0] = (n16 == 0) ? gvv.x : ((n16 == 1) ? ONES : 0u);
                u.u[1] = (n16 == 0) ? gvv.y : ((n16 == 1) ? ONES : 0u);
                u.u[2] = (n16 == 0) ? gvv.z : ((n16 == 1) ? ONES : 0u);
                u.u[3] = (n16 == 0) ? gvv.w : ((n16 == 1) ? ONES : 0u);
                ag = u.s8;
            }
            // B-frag: e_t[d=16w+n16][mmb .. mmb+8)
            const unsigned short* ep = &s_et[16 * w + n16][mmb];
            uint2 e01 = *(const uint2*)(ep);
            uint2 e23 = *(const uint2*)(ep + 4);
            short8 bg;
            {
                U8 u; u.u[0] = e01.x; u.u[1] = e01.y; u.u[2] = e23.x; u.u[3] = e23.y;
                bg = u.s8;
            }
            c2 = __builtin_amdgcn_mfma_f32_16x16x32_bf16(ag, bg, c2, 0, 0, 0);
        }
        __syncthreads();
    }

    // ---- epilogue: softmax divide, final linear (sw, sb)
    if (q4 == 0) s_pre[16 * w + n16] = c2[0] / c2[1];  // row0/row1
    __syncthreads();
    float part = 0.f;
#pragma unroll
    for (int i = 0; i < 16; i++) {
        int r = 16 * w + i;
        part = __builtin_fmaf(s_pre[r], sw[r * 64 + lane], part);
    }
    s_red[w][lane] = part;
    __syncthreads();
    if (tid < 64) {
        float o = s_red[0][tid] + s_red[1][tid] + s_red[2][tid] + s_red[3][tid] + sb[tid];
        out[(size_t)pt * 64 + tid] = o;
    }
    if (pt == 0 && tid == 0) out[(size_t)NPTS * 64] = 1024.0f;  // second output: N
}

extern "C" void kernel_launch(void* const* d_in, const int* in_sizes, int n_in,
                              void* d_out, int out_size, void* d_ws, size_t ws_size,
                              hipStream_t stream) {
    const float* feature = (const float*)d_in[0];
    const float* xyz = (const float*)d_in[1];
    const float* pw1 = (const float*)d_in[2];
    const float* pb1 = (const float*)d_in[3];
    const float* pw2 = (const float*)d_in[4];
    const float* pb2 = (const float*)d_in[5];
    const float* rw = (const float*)d_in[6];
    const float* rb = (const float*)d_in[7];
    const float* sw = (const float*)d_in[8];
    const float* sb = (const float*)d_in[9];
    float* out = (float*)d_out;

    char* ws = (char*)d_ws;
    float* feat = (float*)(ws);                        // 512 KiB
    int* idx = (int*)(ws + 524288);                    // 192 KiB
    unsigned short* rwB = (unsigned short*)(ws + 720896);  // 32 KiB

    prep_mlp_knn_kernel<<<1040, 256, 0, stream>>>(feature, xyz, pw1, pb1, pw2, pb2,
                                                  rw, rb, feat, idx, rwB);
    agg_kernel<<<NPTS, 256, 0, stream>>>(xyz, feat, idx, rwB, sw, sb, out);
}